// Round 7
// baseline (165.552 us; speedup 1.0000x reference)
//
#include <hip/hip_runtime.h>
#include <math.h>

#define B_ 4
#define L_ 4096
#define D_ 256
#define A_ 64
#define M_ (B_*L_)   // 16384 flat rows

typedef _Float16 half4 __attribute__((ext_vector_type(4)));
typedef _Float16 half8 __attribute__((ext_vector_type(8)));
typedef __attribute__((ext_vector_type(4))) float floatx4;

__device__ __forceinline__ unsigned short f2h_(float f) {
    _Float16 h = (_Float16)f;
    return __builtin_bit_cast(unsigned short, h);
}

// ---------------------------------------------------------------------------
// wconv: W f32 [256][64] -> W^T fp16 [64][256]. Wq scaled by 1/ln2 (exp2
// softmax domain). grid (3), block 256.
// ---------------------------------------------------------------------------
__global__ __launch_bounds__(256) void wconv_kernel(
    const float* __restrict__ Wq, const float* __restrict__ Wk,
    const float* __restrict__ Wv, unsigned short* __restrict__ wt)
{
    const int w = blockIdx.x, t = threadIdx.x;
    const float* W = (w == 0) ? Wq : (w == 1) ? Wk : Wv;
    unsigned short* o = wt + w * A_ * D_;
    const float scale = (w == 0) ? 1.44269504f : 1.0f;
    __shared__ float T[A_ * 260];
    #pragma unroll
    for (int p = 0; p < 16; ++p) {
        int idx = p * 256 + t;
        int d = idx >> 4, a4 = (idx & 15) * 4;
        float4 v = *(const float4*)(W + d * A_ + a4);
        T[(a4 + 0) * 260 + d] = v.x * scale;
        T[(a4 + 1) * 260 + d] = v.y * scale;
        T[(a4 + 2) * 260 + d] = v.z * scale;
        T[(a4 + 3) * 260 + d] = v.w * scale;
    }
    __syncthreads();
    const int a = t >> 2, d0 = (t & 3) * 64;
    #pragma unroll
    for (int i = 0; i < 16; ++i) {
        float4 v = *(const float4*)(&T[a * 260 + d0 + 4 * i]);
        ushort4 s;
        s.x = f2h_(v.x); s.y = f2h_(v.y); s.z = f2h_(v.z); s.w = f2h_(v.w);
        *(ushort4*)(o + a * D_ + d0 + 4 * i) = s;
    }
}

// ---------------------------------------------------------------------------
// proj: 16-row blocks, all 3 projections per block. grid (M/16), block 384
// = 6 waves: (w = wid>>1 in {q,k,v}, half = wid&1 -> cols 32*half..+31).
// Per wave: 16 MFMA (2 nt x 8 k-steps); W^T direct from global (L2).
// High TLP (1024 blocks, ~24 waves/CU) hides all latency.
// ---------------------------------------------------------------------------
__global__ __launch_bounds__(384) void proj_kernel(
    const float* __restrict__ x,           // [M][256] f32
    const unsigned short* __restrict__ wt, // [3][64][256] fp16 (W^T)
    unsigned short* __restrict__ qo,
    unsigned short* __restrict__ ko,
    unsigned short* __restrict__ vto)
{
    __shared__ __align__(16) unsigned short Xh[16 * 264];   // 8.25 KB
    __shared__ __align__(16) unsigned short Cst[3840];      // q[16*72] k[16*72] v[64*24]
    const int t = threadIdx.x, m0 = blockIdx.x * 16;

    // stage x tile 16x256 -> fp16 (1024 float4 over 384 threads)
    #pragma unroll
    for (int p = 0; p < 3; ++p) {
        int idx = p * 384 + t;
        if (idx < 1024) {
            int row = idx >> 6, col = (idx & 63) * 4;
            float4 v = *(const float4*)(x + (size_t)(m0 + row) * D_ + col);
            ushort4 s;
            s.x = f2h_(v.x); s.y = f2h_(v.y); s.z = f2h_(v.z); s.w = f2h_(v.w);
            *(ushort4*)(Xh + row * 264 + col) = s;
        }
    }
    __syncthreads();

    const int wid = t >> 6, lane = t & 63, c = lane & 15, g = lane >> 4;
    const int w = wid >> 1, half = wid & 1;

    half8 xa[8];
    #pragma unroll
    for (int s = 0; s < 8; ++s)
        xa[s] = *(const half8*)(Xh + c * 264 + 32 * s + 8 * g);

    const unsigned short* wsrc = wt + w * A_ * D_;
    #pragma unroll
    for (int j = 0; j < 2; ++j) {
        const int nt = 2 * half + j;
        floatx4 acc = {0.f, 0.f, 0.f, 0.f};
        #pragma unroll
        for (int s = 0; s < 8; ++s) {
            half8 wb = *(const half8*)(wsrc + (16 * nt + c) * D_ + 32 * s + 8 * g);
            acc = __builtin_amdgcn_mfma_f32_16x16x32_f16(xa[s], wb, acc, 0, 0, 0);
        }
        // C[m=4g+r][a=16nt+c]
        if (w < 2) {
            #pragma unroll
            for (int r = 0; r < 4; ++r)
                Cst[w * 1152 + (4 * g + r) * 72 + 16 * nt + c] = f2h_(acc[r]);
        } else {
            #pragma unroll
            for (int r = 0; r < 4; ++r)
                Cst[2304 + (16 * nt + c) * 24 + 4 * g + r] = f2h_(acc[r]);
        }
    }
    __syncthreads();

    if (t < 256) {
        const int mat = t >> 7, u = t & 127;
        const int row = u >> 3, seg = u & 7;
        uint4 d = *(const uint4*)(Cst + mat * 1152 + row * 72 + seg * 8);
        unsigned short* o = mat ? ko : qo;
        *(uint4*)(o + (size_t)(m0 + row) * A_ + seg * 8) = d;
    } else {
        const int u = t - 256, a = u >> 1, hh = u & 1;
        uint4 d = *(const uint4*)(Cst + 2304 + a * 24 + hh * 8);
        const int bb = m0 >> 12, l0 = m0 & (L_ - 1);
        *(uint4*)(vto + ((size_t)(bb * A_ + a)) * L_ + l0 + hh * 8) = d;
    }
}

// ---------------------------------------------------------------------------
// attn: 64-q blocks x 4-way split-K, register-staged double-buffer pipeline.
// grid (256, B): bx -> (qtile = 63-(bx>>2), h = bx&3). T = qtile+1 tiles;
// block handles kt in [hT/4, (h+1)T/4). 4 waves = 4 qsubs (16 q each).
// Per tile: prefetch next K/V tile to VGPRs BEFORE compute, ds_write after,
// ONE barrier -> global latency hides under MFMA+softmax.
// S^T form: QK^T A=K,B=Q -> S^T[key][q=c]; softmax per-lane q (exp2);
// PV: A=V^T 8B LDS frags, B=P^T in regs (K=16 chain).
// Partials (unnormalized O, m, l): h=0 -> out, h>=1 -> pb. Empty range ->
// O=0, m=-inf, l=0 (merge weights to zero).
// ---------------------------------------------------------------------------
__global__ __launch_bounds__(256) void attn_kernel(
    const unsigned short* __restrict__ qb,  // [B][L][64] fp16 (x 1/ln2)
    const unsigned short* __restrict__ kb,  // [B][L][64] fp16
    const unsigned short* __restrict__ vt,  // [B][64][L] fp16
    float* __restrict__ out,                // partial O for h=0
    float* __restrict__ pb,                 // partials h=1..3 (3 x M*A)
    float2* __restrict__ mlb)               // (m,l) [4][M]
{
    __shared__ __align__(16) unsigned short smem[18432];  // 36 KB: K 2buf + V 2buf
    const int t    = threadIdx.x;
    const int lane = t & 63;
    const int wid  = t >> 6;          // qsub
    const int c    = lane & 15;
    const int g    = lane >> 4;
    const int b    = blockIdx.y;
    const int bx   = blockIdx.x;
    const int qtile = 63 - (bx >> 2); // heavy q-tiles first
    const int h    = bx & 3;
    const int q0   = qtile * 64;
    const int qrow0 = q0 + 16 * wid;
    const int qme  = qrow0 + c;

    const size_t base  = (size_t)b * L_ * A_;
    const size_t vbase = (size_t)b * A_ * L_;

    half8 qf[2];
    {
        const unsigned short* qp = qb + base + (size_t)(qrow0 + c) * A_ + g * 8;
        qf[0] = *(const half8*)(qp);
        qf[1] = *(const half8*)(qp + 32);
    }

    floatx4 O4[4];          // O^T[a=16at+4g+r][q=c], unnormalized
    #pragma unroll
    for (int at = 0; at < 4; ++at) O4[at] = (floatx4){0.f, 0.f, 0.f, 0.f};
    float m_ = -INFINITY, l_ = 0.f;

    const int T  = qtile + 1;
    const int t0 = (h * T) >> 2;
    const int t1 = ((h + 1) * T) >> 2;
    const int nT = t1 - t0;           // block-uniform

    const int srow = t >> 3, sc8 = t & 7;   // staging thread map (+256: rows +32)

    if (nT > 0) {
        // prologue: stage tile t0 into buffer 0
        {
            const size_t k0e = (size_t)t0 << 6;
            #pragma unroll
            for (int i = 0; i < 2; ++i) {
                const int cid = t + (i << 8);
                const int row = srow + (i << 5);
                uint4 dK = *(const uint4*)(kb + base + k0e * 64 + cid * 8);
                uint4 dV = *(const uint4*)(vt + vbase + (size_t)row * L_ + k0e + sc8 * 8);
                *(uint4*)(smem + row * 72 + sc8 * 8) = dK;
                *(uint4*)(smem + 9216 + row * 72 + sc8 * 8) = dV;
            }
        }
        __syncthreads();

        for (int i = 0; i < nT; ++i) {
            const int kt = t0 + i;
            const int k0 = kt << 6;
            const bool pf = (i + 1 < nT);
            uint4 nK[2], nV[2];
            if (pf) {                          // prefetch next tile -> VGPRs
                const size_t k0n = (size_t)(kt + 1) << 6;
                #pragma unroll
                for (int u = 0; u < 2; ++u) {
                    const int cid = t + (u << 8);
                    const int row = srow + (u << 5);
                    nK[u] = *(const uint4*)(kb + base + k0n * 64 + cid * 8);
                    nV[u] = *(const uint4*)(vt + vbase + (size_t)row * L_ + k0n + sc8 * 8);
                }
            }
            const unsigned short* Kw = smem + (i & 1) * 4608;
            const unsigned short* Vw = smem + 9216 + (i & 1) * 4608;

            // ---- S^T = K . Q^T ----
            floatx4 S4[4];
            #pragma unroll
            for (int nt = 0; nt < 4; ++nt) S4[nt] = (floatx4){0.f, 0.f, 0.f, 0.f};
            #pragma unroll
            for (int s = 0; s < 2; ++s)
                #pragma unroll
                for (int nt = 0; nt < 4; ++nt) {
                    half8 kf = *(const half8*)(Kw + (16 * nt + c) * 72 + 32 * s + 8 * g);
                    S4[nt] = __builtin_amdgcn_mfma_f32_16x16x32_f16(kf, qf[s], S4[nt], 0, 0, 0);
                }

            // ---- causal mask: only global tile T-1 straddles the diagonal ----
            if (kt == T - 1) {
                #pragma unroll
                for (int nt = 0; nt < 4; ++nt)
                    #pragma unroll
                    for (int r = 0; r < 4; ++r)
                        if (k0 + 16 * nt + 4 * g + r > qme) S4[nt][r] = -INFINITY;
            }

            // ---- online softmax (exp2 domain; per-lane q row) ----
            float tm = fmaxf(fmaxf(fmaxf(S4[0][0], S4[0][1]), fmaxf(S4[0][2], S4[0][3])),
                             fmaxf(fmaxf(S4[1][0], S4[1][1]), fmaxf(S4[1][2], S4[1][3])));
            tm = fmaxf(tm, fmaxf(fmaxf(fmaxf(S4[2][0], S4[2][1]), fmaxf(S4[2][2], S4[2][3])),
                                 fmaxf(fmaxf(S4[3][0], S4[3][1]), fmaxf(S4[3][2], S4[3][3]))));
            tm = fmaxf(tm, __shfl_xor(tm, 16));
            tm = fmaxf(tm, __shfl_xor(tm, 32));
            const float mn  = fmaxf(m_, tm);
            const float mnc = fmaxf(mn, -3.0e38f);         // guard -inf - -inf
            const float al  = exp2f(fminf(m_ - mnc, 0.f)); // m_=-inf -> 0
            float rs = 0.f;
            half4 pfr[4];
            #pragma unroll
            for (int nt = 0; nt < 4; ++nt) {
                #pragma unroll
                for (int r = 0; r < 4; ++r) {
                    float p = exp2f(S4[nt][r] - mnc);      // masked: exp2(-inf)=0
                    S4[nt][r] = p;
                    rs += p;
                }
                pfr[nt][0] = (_Float16)S4[nt][0];
                pfr[nt][1] = (_Float16)S4[nt][1];
                pfr[nt][2] = (_Float16)S4[nt][2];
                pfr[nt][3] = (_Float16)S4[nt][3];
            }
            rs += __shfl_xor(rs, 16);
            rs += __shfl_xor(rs, 32);
            l_ = l_ * al + rs;
            m_ = mn;

            // ---- O^T = O^T*al + V^T . P^T ----
            #pragma unroll
            for (int at = 0; at < 4; ++at) {
                O4[at] *= al;
                #pragma unroll
                for (int nt = 0; nt < 4; ++nt) {
                    half4 va = *(const half4*)(Vw + (16 * at + c) * 72 + 16 * nt + 4 * g);
                    O4[at] = __builtin_amdgcn_mfma_f32_16x16x16f16(va, pfr[nt], O4[at], 0, 0, 0);
                }
            }

            if (pf) {                          // write prefetched tile -> other buffer
                const int bsel = (i + 1) & 1;
                #pragma unroll
                for (int u = 0; u < 2; ++u) {
                    const int row = srow + (u << 5);
                    *(uint4*)(smem + bsel * 4608 + row * 72 + sc8 * 8) = nK[u];
                    *(uint4*)(smem + 9216 + bsel * 4608 + row * 72 + sc8 * 8) = nV[u];
                }
            }
            __syncthreads();
        }
    }

    // ---- epilogue: un-transpose via LDS, store unnormalized partial ----
    float* Ot = (float*)smem;                 // [4 waves][16 q][68 a] = 17.4 KB
    #pragma unroll
    for (int at = 0; at < 4; ++at)
        #pragma unroll
        for (int r = 0; r < 4; ++r)
            Ot[wid * 1088 + c * 68 + 16 * at + 4 * g + r] = O4[at][r];
    if (g == 0) {
        float2 ml; ml.x = m_; ml.y = l_;
        mlb[(size_t)h * M_ + b * L_ + qrow0 + c] = ml;
    }
    __syncthreads();
    {
        const int q = t >> 2, seg = t & 3;
        float* PO = (h == 0) ? out : (pb + (size_t)(h - 1) * M_ * A_);
        const float* src = Ot + (q >> 4) * 1088 + (q & 15) * 68 + seg * 16;
        float* dst = PO + base + (size_t)(q0 + q) * A_ + seg * 16;
        #pragma unroll
        for (int u = 0; u < 4; ++u)
            *(float4*)(dst + 4 * u) = *(const float4*)(src + 4 * u);
    }
}

// ---------------------------------------------------------------------------
// merge: final = sum_h(O_h * w_h) / sum_h(l_h * w_h). grid (1024), block 256.
// ---------------------------------------------------------------------------
__global__ __launch_bounds__(256) void merge_kernel(
    float* __restrict__ out, const float* __restrict__ pb,
    const float2* __restrict__ mlb)
{
    const int tg = blockIdx.x * 256 + threadIdx.x;   // 262144 float4s
    const int q = tg >> 4;
    const float2 a0 = mlb[q];
    const float2 a1 = mlb[M_ + q];
    const float2 a2 = mlb[2 * M_ + q];
    const float2 a3 = mlb[3 * M_ + q];
    const float mf = fmaxf(fmaxf(a0.x, a1.x), fmaxf(a2.x, a3.x));
    const float mc = fmaxf(mf, -3.0e38f);
    const float w0 = exp2f(a0.x - mc), w1 = exp2f(a1.x - mc);
    const float w2 = exp2f(a2.x - mc), w3 = exp2f(a3.x - mc);
    const float inv = 1.f / (w0 * a0.y + w1 * a1.y + w2 * a2.y + w3 * a3.y);
    const float4 o0 = ((const float4*)out)[tg];
    const float4 o1 = ((const float4*)(pb))[tg];
    const float4 o2 = ((const float4*)(pb + (size_t)M_ * A_))[tg];
    const float4 o3 = ((const float4*)(pb + (size_t)2 * M_ * A_))[tg];
    float4 r;
    r.x = (o0.x * w0 + o1.x * w1 + o2.x * w2 + o3.x * w3) * inv;
    r.y = (o0.y * w0 + o1.y * w1 + o2.y * w2 + o3.y * w3) * inv;
    r.z = (o0.z * w0 + o1.z * w1 + o2.z * w2 + o3.z * w3) * inv;
    r.w = (o0.w * w0 + o1.w * w1 + o2.w * w2 + o3.w * w3) * inv;
    ((float4*)out)[tg] = r;
}

// ---------------------------------------------------------------------------
extern "C" void kernel_launch(void* const* d_in, const int* in_sizes, int n_in,
                              void* d_out, int out_size, void* d_ws, size_t ws_size,
                              hipStream_t stream) {
    const float* x  = (const float*)d_in[0];
    const float* Wq = (const float*)d_in[1];
    const float* Wk = (const float*)d_in[2];
    const float* Wv = (const float*)d_in[3];

    char* ws = (char*)d_ws;
    unsigned short* qb = (unsigned short*)(ws);                      // 2 MB
    unsigned short* kb = (unsigned short*)(ws + (2u << 20));         // 2 MB
    unsigned short* vt = (unsigned short*)(ws + (4u << 20));         // 2 MB
    unsigned short* wt = (unsigned short*)(ws + (6u << 20));         // 96 KB (pad 128)
    float*  pbuf = (float*) (ws + (6u << 20) + (128u << 10));        // 12 MB (h=1..3)
    float2* mlb  = (float2*)(ws + (18u << 20) + (128u << 10));       // 512 KB
    float* out = (float*)d_out;

    hipLaunchKernelGGL(wconv_kernel, dim3(3), dim3(256), 0, stream, Wq, Wk, Wv, wt);
    hipLaunchKernelGGL(proj_kernel, dim3(M_ / 16), dim3(384), 0, stream, x, wt, qb, kb, vt);
    hipLaunchKernelGGL(attn_kernel, dim3(256, B_), dim3(256), 0, stream,
                       qb, kb, vt, out, pbuf, mlb);
    hipLaunchKernelGGL(merge_kernel, dim3(1024), dim3(256), 0, stream, out, pbuf, mlb);
}